// Round 3
// baseline (5684.583 us; speedup 1.0000x reference)
//
#include <hip/hip_runtime.h>
#include <hip/hip_fp16.h>

typedef unsigned int u32;
typedef unsigned short u16;
typedef _Float16 half2v __attribute__((ext_vector_type(2)));

#define N_UNITS 512
#define N_ORDER 256
#define N_T     1024
#define N_B     64
#define KWG     4
#define PKT_STRIDE 288   // dwords per (parity,b,q) packet: 128 m + 128 h + 16 u

__device__ inline float dot2f(u32 a, u32 b, float acc) {
    return __builtin_amdgcn_fdot2(__builtin_bit_cast(half2v, a),
                                  __builtin_bit_cast(half2v, b), acc, false);
}
__device__ inline u16 f2h_bits(float v) {
    _Float16 f = (_Float16)v;
    return __builtin_bit_cast(u16, f);
}
__device__ inline float hbits2f(u32 dw) {
    u16 s = (u16)(dw & 0xFFFFu);
    _Float16 f = __builtin_bit_cast(_Float16, s);
    return (float)f;
}
__device__ inline u32 pack_h2(float a, float b) {
    return (u32)f2h_bits(a) | ((u32)f2h_bits(b) << 16);
}
__device__ inline u32 aload(const u32* p) {
    return __hip_atomic_load(p, __ATOMIC_RELAXED, __HIP_MEMORY_SCOPE_AGENT);
}
__device__ inline void astore(u32* p, u32 v) {
    __hip_atomic_store(p, v, __ATOMIC_RELAXED, __HIP_MEMORY_SCOPE_AGENT);
}

// hk2[kk][c] = half2(hk[2kk][c], hk[2kk+1][c]),  kk<256, c<512
__global__ __launch_bounds__(256)
void prep_hk(const float* __restrict__ hk, u32* __restrict__ hk2) {
    int tid = blockIdx.x * 256 + threadIdx.x;   // 131072 total
    int kk = tid >> 9, c = tid & 511;
    hk2[tid] = pack_h2(hk[(2 * kk) * 512 + c], hk[(2 * kk + 1) * 512 + c]);
}

// AMK = mk + AT@mk  (fp16, j-pair packed);  BMK = BT@mk (fp32)
__global__ __launch_bounds__(512)
void prep_amk(const float* __restrict__ mk, const float* __restrict__ at,
              const float* __restrict__ bt,
              u32* __restrict__ amk2, float* __restrict__ bmk) {
    int bj = blockIdx.x, c = threadIdx.x;
    if (bj < 128) {
        int j0 = 2 * bj, j1 = j0 + 1;
        float a0 = mk[j0 * 512 + c];
        float a1 = mk[j1 * 512 + c];
        #pragma unroll 8
        for (int k = 0; k < 256; ++k) {
            float w = mk[k * 512 + c];
            a0 = fmaf(at[j0 * 256 + k], w, a0);
            a1 = fmaf(at[j1 * 256 + k], w, a1);
        }
        amk2[bj * 512 + c] = pack_h2(a0, a1);
    } else {
        float s = 0.f;
        #pragma unroll 8
        for (int k = 0; k < 256; ++k) s = fmaf(bt[k], mk[k * 512 + c], s);
        bmk[c] = s;
    }
}

// K=4 WGs per batch; grid=256 (1 WG/CU). g: b=g&63, q=g>>6 (same XCD mod-8).
// WG q owns h cols [128q,+128), m rows [64q,+64).
// Round-3: SINGLE barrier per step. k-split partials live in adjacent lanes
// (quad for z, octet for AT) and reduce via __shfl_xor — no cross-wave LDS
// reduction, so B2/B3 are gone. All shared state is parity double-buffered;
// the one B1 (needed for the poll anyway) provides all ordering. LDS state
// is group-padded (bases on banks {0,8,16,24}/{0,4..28}) so the 4/8 distinct
// broadcast addresses per ds_read_b128 are conflict-free with immediate offsets.
__global__ __launch_bounds__(512, 2)
void lmu_main(const float* __restrict__ x, const float* __restrict__ ie,
              const float* __restrict__ he, const float* __restrict__ me,
              const float* __restrict__ ik, const float* __restrict__ bt,
              const float* __restrict__ at,
              const u32* __restrict__ hk2, const u32* __restrict__ amk2,
              const float* __restrict__ bmk,
              u32* __restrict__ pkt, float* __restrict__ out) {
    __shared__ float xs[N_T];
    __shared__ float he_sl[128], ik_sl[128], bmk_sl[128];
    __shared__ float me_sl[64], bt_sl[64];
    // parity-double-buffered state, grouped + padded:
    //   hst : h j-pair half2, 4 groups x (64 used + 8 pad) u32
    //   mhst/mlst: m hi/lo j-pair half2, 4 groups x (32 used + 8 pad) u32
    //   mfst: m fp32, 8 groups x (32 used + 4 pad) f32
    __shared__ __align__(16) u32   hst[2][288];
    __shared__ __align__(16) u32   mhst[2][160], mlst[2][160];
    __shared__ __align__(16) float mfst[2][288];
    __shared__ __align__(16) float uvals[2][16];  // [par][0..7]=peer halves, [8..15]=own per-wave

    const int tid = threadIdx.x;
    const int g = blockIdx.x, b = g & 63, q = g >> 6;
    const int w = tid >> 6, l = tid & 63;
    const int kk  = l & 3;            // z k-group (quad)
    const int cl  = 16 * w + (l >> 2);// own h column 0..127
    const int C   = 128 * q + cl;     // global column
    const int k8  = l & 7;            // AT k-group (octet)
    const int jl2 = 8 * w + (l >> 3); // own m row 0..63
    const int J   = 64 * q + jl2;     // global row

    // own-slice write indices into padded state
    const int HW16 = 144 * q + cl;                       // u16 idx in hst
    const int MW16 = 80 * q + jl2;                       // u16 idx in mhst/mlst
    const int MFW  = 36 * (2 * q + (jl2 >> 5)) + (jl2 & 31);

    // ---- preload LDS ----
    for (int i = tid; i < N_T; i += 512) xs[i] = x[b * N_T + i];
    if (tid < 128) {
        he_sl[tid]  = he[128 * q + tid];
        ik_sl[tid]  = ik[128 * q + tid];
        bmk_sl[tid] = bmk[128 * q + tid];
    }
    if (tid < 64) { me_sl[tid] = me[64 * q + tid]; bt_sl[tid] = bt[64 * q + tid]; }
    for (int i = tid; i < 2 * 288; i += 512) {
        (&hst[0][0])[i] = 0u;
        (&mfst[0][0])[i] = 0.f;
    }
    for (int i = tid; i < 2 * 160; i += 512) {
        (&mhst[0][0])[i] = 0u;
        (&mlst[0][0])[i] = 0u;
    }
    if (tid < 32) (&uvals[0][0])[tid] = 0.f;
    const float ie0 = ie[0];

    // ---- weights into registers (once; compiler hosts in AGPRs) ----
    u32 hk_w[64];
    #pragma unroll
    for (int i = 0; i < 64; ++i)
        hk_w[i] = hk2[(size_t)(64 * kk + i) * 512 + C];
    u32 amk_w[32];
    #pragma unroll
    for (int i = 0; i < 32; ++i)
        amk_w[i] = amk2[(size_t)(32 * kk + i) * 512 + C];
    float at_w[32];
    #pragma unroll
    for (int i = 0; i < 32; ++i)
        at_w[i] = at[(size_t)(32 * k8 + i) * 256 + J];

    __syncthreads();

    float* outb = out + (size_t)b * N_T * N_UNITS;

    for (int t = 0; t < N_T; ++t) {
        const int sb = t & 1;

        // ---- consume peers' packets into buf[sb] (pre-barrier) ----
        if (t > 0 && tid < 198) {
            const u32 ep  = (u32)t;
            const int par = (t - 1) & 1;
            if (tid < 192) {
                const int pi = tid >> 6;
                const int q2 = pi + (pi >= q ? 1 : 0);
                const u32* base = pkt + (size_t)(par * 256 + b * 4 + q2) * PKT_STRIDE;
                const int i = tid & 63;
                u32 d0, d1, d2, d3;
                for (;;) {
                    d0 = aload(base + 4 * i + 0);
                    d1 = aload(base + 4 * i + 1);
                    d2 = aload(base + 4 * i + 2);
                    d3 = aload(base + 4 * i + 3);
                    if (((((d0 >> 16) ^ ep) | ((d1 >> 16) ^ ep)) |
                         (((d2 >> 16) ^ ep) | ((d3 >> 16) ^ ep))) == 0) break;
                }
                if (i < 32) {          // m rows 2i,2i+1 (hi,lo dword pairs)
                    mhst[sb][40 * q2 + i] = (d0 & 0xFFFFu) | (d2 << 16);
                    mlst[sb][40 * q2 + i] = (d1 & 0xFFFFu) | (d3 << 16);
                    float2 v;
                    v.x = hbits2f(d0) + hbits2f(d1);
                    v.y = hbits2f(d2) + hbits2f(d3);
                    *reinterpret_cast<float2*>(
                        &mfst[sb][36 * (2 * q2 + (i >> 4)) + ((2 * i) & 31)]) = v;
                } else {               // h cols 4(i-32)..+3 of peer slice
                    const int dl = 2 * (i - 32);
                    hst[sb][72 * q2 + dl]     = (d0 & 0xFFFFu) | (d1 << 16);
                    hst[sb][72 * q2 + dl + 1] = (d2 & 0xFFFFu) | (d3 << 16);
                }
            } else {                   // u: 8 dwords = 4 per-wave hi/lo pairs
                const int ui = tid - 192;           // 0..5
                const int pi = ui >> 1, half = ui & 1;
                const int q2 = pi + (pi >= q ? 1 : 0);
                const u32* p8 = pkt + (size_t)(par * 256 + b * 4 + q2) * PKT_STRIDE
                              + 256 + 8 * half;
                u32 d0, d1, d2, d3, d4, d5, d6, d7;
                for (;;) {
                    d0 = aload(p8 + 0); d1 = aload(p8 + 1);
                    d2 = aload(p8 + 2); d3 = aload(p8 + 3);
                    d4 = aload(p8 + 4); d5 = aload(p8 + 5);
                    d6 = aload(p8 + 6); d7 = aload(p8 + 7);
                    u32 bad = ((((d0 >> 16) ^ ep) | ((d1 >> 16) ^ ep)) |
                               (((d2 >> 16) ^ ep) | ((d3 >> 16) ^ ep))) |
                              ((((d4 >> 16) ^ ep) | ((d5 >> 16) ^ ep)) |
                               (((d6 >> 16) ^ ep) | ((d7 >> 16) ^ ep)));
                    if (bad == 0) break;
                }
                uvals[sb][2 * q2 + half] =
                    ((hbits2f(d0) + hbits2f(d1)) + (hbits2f(d2) + hbits2f(d3)))
                  + ((hbits2f(d4) + hbits2f(d5)) + (hbits2f(d6) + hbits2f(d7)));
            }
        }
        __syncthreads();                     // B1 — the ONLY barrier per step

        // ---- z partials: h@hk + (m_hi+m_lo)@AMK, k-split across quad ----
        const uint4*  h4g  = reinterpret_cast<const uint4*>(&hst[sb][0])  + 18 * kk;
        const uint4*  mh4g = reinterpret_cast<const uint4*>(&mhst[sb][0]) + 10 * kk;
        const uint4*  ml4g = reinterpret_cast<const uint4*>(&mlst[sb][0]) + 10 * kk;
        const float4* mf4g = reinterpret_cast<const float4*>(&mfst[sb][0]) + 9 * k8;

        float z0 = 0.f, z1 = 0.f, z2 = 0.f, z3 = 0.f;
        #pragma unroll
        for (int j = 0; j < 16; ++j) {
            uint4 hv = h4g[j];
            z0 = dot2f(hv.x, hk_w[4 * j + 0], z0);
            z1 = dot2f(hv.y, hk_w[4 * j + 1], z1);
            z2 = dot2f(hv.z, hk_w[4 * j + 2], z2);
            z3 = dot2f(hv.w, hk_w[4 * j + 3], z3);
        }
        #pragma unroll
        for (int j = 0; j < 8; ++j) {
            uint4 mh = mh4g[j], ml = ml4g[j];
            z0 = dot2f(mh.x, amk_w[4 * j + 0], z0); z0 = dot2f(ml.x, amk_w[4 * j + 0], z0);
            z1 = dot2f(mh.y, amk_w[4 * j + 1], z1); z1 = dot2f(ml.y, amk_w[4 * j + 1], z1);
            z2 = dot2f(mh.z, amk_w[4 * j + 2], z2); z2 = dot2f(ml.z, amk_w[4 * j + 2], z2);
            z3 = dot2f(mh.w, amk_w[4 * j + 3], z3); z3 = dot2f(ml.w, amk_w[4 * j + 3], z3);
        }
        float z = (z0 + z1) + (z2 + z3);
        z += __shfl_xor(z, 1); z += __shfl_xor(z, 2);   // full column dot in quad

        // ---- AT partials: (m@AT)[J], k-split across octet ----
        float a0 = 0.f, a1 = 0.f, a2 = 0.f, a3 = 0.f;
        #pragma unroll
        for (int j = 0; j < 8; ++j) {
            float4 mv = mf4g[j];
            a0 = fmaf(mv.x, at_w[4 * j + 0], a0);
            a1 = fmaf(mv.y, at_w[4 * j + 1], a1);
            a2 = fmaf(mv.z, at_w[4 * j + 2], a2);
            a3 = fmaf(mv.w, at_w[4 * j + 3], a3);
        }
        float am = (a0 + a1) + (a2 + a3);
        am += __shfl_xor(am, 1); am += __shfl_xor(am, 2); am += __shfl_xor(am, 4);

        // ---- u (every thread, broadcast reads) ----
        const float4* uvp = reinterpret_cast<const float4*>(&uvals[sb][0]);
        float4 ua = uvp[0], ub2 = uvp[1], uc = uvp[2], ud = uvp[3];
        const float u = ((((ua.x + ua.y) + (ua.z + ua.w)) + ((ub2.x + ub2.y) + (ub2.z + ub2.w)))
                      +  (((uc.x + uc.y) + (uc.z + uc.w)) + ((ud.x + ud.y) + (ud.z + ud.w))))
                      + xs[t] * ie0;

        const bool pub = (t < N_T - 1);
        const u32 eph  = (u32)(t + 1) << 16;
        u32* myb = pkt + (size_t)(sb * 256 + b * 4 + q) * PKT_STRIDE;

        // ---- m finalize (redundant per octet; lane l&7==0 commits) ----
        const float mnew = mfst[sb][MFW] + u * bt_sl[jl2] + am;
        const _Float16 mh_f = (_Float16)mnew;
        const u16 mhi_b = __builtin_bit_cast(u16, mh_f);
        const u16 mlo_b = f2h_bits(mnew - (float)mh_f);
        if ((l & 7) == 0) {
            if (pub) {
                astore(myb + 2 * jl2,     (u32)mhi_b | eph);
                astore(myb + 2 * jl2 + 1, (u32)mlo_b | eph);
            }
            reinterpret_cast<u16*>(&mhst[sb ^ 1][0])[MW16] = mhi_b;
            reinterpret_cast<u16*>(&mlst[sb ^ 1][0])[MW16] = mlo_b;
            mfst[sb ^ 1][MFW] = mnew;
        }

        // ---- h finalize (redundant per quad; lane l&3==0 commits) ----
        const float zf = z + xs[t] * ik_sl[cl] + u * bmk_sl[cl];
        const float hnew = tanhf(zf);
        const u16 hb = f2h_bits(hnew);
        if ((l & 3) == 0) {
            if (pub) astore(myb + 128 + cl, (u32)hb | eph);
            outb[(size_t)t * N_UNITS + C] = hnew;
            reinterpret_cast<u16*>(&hst[sb ^ 1][0])[HW16] = hb;
        }

        // ---- own u-partials for t+1: per-wave in-wave reduce + publish ----
        if (pub) {
            float up = ((l & 3) == 0) ? hnew * he_sl[cl] : 0.f;
            if ((l & 7) == 0) up = fmaf(mnew, me_sl[jl2], up);
            up += __shfl_xor(up, 1);  up += __shfl_xor(up, 2);
            up += __shfl_xor(up, 4);  up += __shfl_xor(up, 8);
            up += __shfl_xor(up, 16); up += __shfl_xor(up, 32);
            if (l == 0) {
                uvals[sb ^ 1][8 + w] = up;
                const _Float16 hi = (_Float16)up;
                astore(myb + 256 + 2 * w,     (u32)__builtin_bit_cast(u16, hi) | eph);
                astore(myb + 256 + 2 * w + 1, (u32)f2h_bits(up - (float)hi) | eph);
            }
        }
    }
}

extern "C" void kernel_launch(void* const* d_in, const int* in_sizes, int n_in,
                              void* d_out, int out_size, void* d_ws, size_t ws_size,
                              hipStream_t stream) {
    const float* x  = (const float*)d_in[0];
    const float* ie = (const float*)d_in[1];
    const float* he = (const float*)d_in[2];
    const float* me = (const float*)d_in[3];
    const float* ik = (const float*)d_in[4];
    const float* hk = (const float*)d_in[5];
    const float* mk = (const float*)d_in[6];
    const float* at = (const float*)d_in[7];
    const float* bt = (const float*)d_in[8];

    u32*   hk2  = (u32*)d_ws;                   // 131072 u32 = 512 KB
    u32*   amk2 = hk2 + 256 * 512;              //  65536 u32 = 256 KB
    float* bmk  = (float*)(amk2 + 128 * 512);   //    512 f32 =   2 KB
    u32*   pkt  = (u32*)(bmk + 512);            // 2*64*4*288 u32 = 576 KB

    prep_hk<<<512, 256, 0, stream>>>(hk, hk2);
    prep_amk<<<129, 512, 0, stream>>>(mk, at, bt, amk2, bmk);
    lmu_main<<<N_B * KWG, 512, 0, stream>>>(x, ie, he, me, ik, bt, at,
                                            hk2, amk2, bmk, pkt, (float*)d_out);
}

// Round 4
// 3258.796 us; speedup vs baseline: 1.7444x; 1.7444x over previous
//
#include <hip/hip_runtime.h>
#include <hip/hip_fp16.h>

typedef unsigned int u32;
typedef unsigned short u16;
typedef _Float16 half2v __attribute__((ext_vector_type(2)));

#define N_UNITS 512
#define N_ORDER 256
#define N_T     1024
#define N_B     64
#define KWG     4
#define PKT_STRIDE 288   // dwords per (parity,b,q) packet: 128 m + 128 h + 4 u + pad

__device__ inline float dot2f(u32 a, u32 b, float acc) {
    return __builtin_amdgcn_fdot2(__builtin_bit_cast(half2v, a),
                                  __builtin_bit_cast(half2v, b), acc, false);
}
__device__ inline u16 f2h_bits(float v) {
    _Float16 f = (_Float16)v;
    return __builtin_bit_cast(u16, f);
}
__device__ inline float hbits2f(u32 dw) {
    u16 s = (u16)(dw & 0xFFFFu);
    _Float16 f = __builtin_bit_cast(_Float16, s);
    return (float)f;
}
__device__ inline u32 pack_h2(float a, float b) {
    return (u32)f2h_bits(a) | ((u32)f2h_bits(b) << 16);
}
__device__ inline u32 aload(const u32* p) {
    return __hip_atomic_load(p, __ATOMIC_RELAXED, __HIP_MEMORY_SCOPE_AGENT);
}
__device__ inline void astore(u32* p, u32 v) {
    __hip_atomic_store(p, v, __ATOMIC_RELAXED, __HIP_MEMORY_SCOPE_AGENT);
}

// hk2[kk][c] = half2(hk[2kk][c], hk[2kk+1][c]),  kk<256, c<512
__global__ __launch_bounds__(256)
void prep_hk(const float* __restrict__ hk, u32* __restrict__ hk2) {
    int tid = blockIdx.x * 256 + threadIdx.x;   // 131072 total
    int kk = tid >> 9, c = tid & 511;
    hk2[tid] = pack_h2(hk[(2 * kk) * 512 + c], hk[(2 * kk + 1) * 512 + c]);
}

// AMK = mk + AT@mk  (fp16, j-pair packed);  BMK = BT@mk (fp32)
__global__ __launch_bounds__(512)
void prep_amk(const float* __restrict__ mk, const float* __restrict__ at,
              const float* __restrict__ bt,
              u32* __restrict__ amk2, float* __restrict__ bmk) {
    int bj = blockIdx.x, c = threadIdx.x;
    if (bj < 128) {
        int j0 = 2 * bj, j1 = j0 + 1;
        float a0 = mk[j0 * 512 + c];
        float a1 = mk[j1 * 512 + c];
        #pragma unroll 8
        for (int k = 0; k < 256; ++k) {
            float w = mk[k * 512 + c];
            a0 = fmaf(at[j0 * 256 + k], w, a0);
            a1 = fmaf(at[j1 * 256 + k], w, a1);
        }
        amk2[bj * 512 + c] = pack_h2(a0, a1);
    } else {
        float s = 0.f;
        #pragma unroll 8
        for (int k = 0; k < 256; ++k) s = fmaf(bt[k], mk[k * 512 + c], s);
        bmk[c] = s;
    }
}

// K=4 WGs per batch; grid=256 (1 WG/CU). g: b=g&63, q=g>>6 (same XCD mod-8).
// WG q owns h cols [128q,128q+128), m cols [64q,64q+64).
// Round-4 delta vs the proven 2887us kernel (R0), everything else identical:
//   * u-partials are NOT polled at top-of-step. Finalize threads spin-read
//     all 4 WGs' u-pairs directly from global (published one step earlier,
//     so the RTT is hidden behind the z-phase).
//   * Each of waves 0/1 publishes its own u hi/lo pair right after its
//     shfl reduce (2 pairs/WG) — no B3, no tid0 funnel on the publish tail.
//   * B3 removed entirely (B1 fences the zbuf/ampart WAR hazard).
__global__ __launch_bounds__(512, 2)
void lmu_main(const float* __restrict__ x, const float* __restrict__ ie,
              const float* __restrict__ he, const float* __restrict__ me,
              const float* __restrict__ ik, const float* __restrict__ bt,
              const float* __restrict__ at,
              const u32* __restrict__ hk2, const u32* __restrict__ amk2,
              const float* __restrict__ bmk,
              u32* __restrict__ pkt, float* __restrict__ out) {
    __shared__ float xs[N_T];
    __shared__ float he_sl[128], ik_sl[128], bmk_sl[128];
    __shared__ float me_sl[64], bt_sl[64];
    __shared__ __align__(8) u16 h_h16[N_UNITS];     // full h, fp16
    __shared__ __align__(8) u16 m_hi16[N_ORDER], m_lo16[N_ORDER];
    __shared__ __align__(8) float mf[N_ORDER];      // full m, fp32(-ish)
    __shared__ float zbuf[512], ampart[512];

    const int tid = threadIdx.x;
    const int g   = blockIdx.x;
    const int b   = g & 63;
    const int q   = g >> 6;
    const int kg  = tid >> 7;        // 0..3 (hk/AMK k-group)
    const int cl  = tid & 127;       // col within own h slice
    const int kg8 = tid >> 6;        // 0..7 (AT k-group)
    const int jl  = tid & 63;
    const int J   = 64 * q + jl;
    const int lane = tid & 63;

    // ---- preload LDS ----
    for (int i = tid; i < N_T; i += 512) xs[i] = x[b * N_T + i];
    if (tid < 128) {
        he_sl[tid]  = he[128 * q + tid];
        ik_sl[tid]  = ik[128 * q + tid];
        bmk_sl[tid] = bmk[128 * q + tid];
    }
    if (tid < 64) { me_sl[tid] = me[J]; bt_sl[tid] = bt[J]; }
    h_h16[tid] = 0;
    if (tid < 256) { m_hi16[tid] = 0; m_lo16[tid] = 0; mf[tid] = 0.f; }
    const float ie0 = ie[0];

    // ---- weights into registers (once) ----
    u32 hk_w[64];
    #pragma unroll
    for (int i = 0; i < 64; ++i)
        hk_w[i] = hk2[(size_t)(64 * kg + i) * 512 + 128 * q + cl];
    u32 amk_w[32];
    #pragma unroll
    for (int i = 0; i < 32; ++i)
        amk_w[i] = amk2[(size_t)(32 * kg + i) * 512 + 128 * q + cl];
    float at_w[32];
    #pragma unroll
    for (int i = 0; i < 32; ++i)
        at_w[i] = at[(size_t)(32 * kg8 + i) * 256 + J];

    __syncthreads();

    const u32* h2u   = reinterpret_cast<const u32*>(h_h16);
    const u32* m_hi2 = reinterpret_cast<const u32*>(m_hi16);
    const u32* m_lo2 = reinterpret_cast<const u32*>(m_lo16);
    float* outb = out + (size_t)b * N_T * N_UNITS;

    for (int t = 0; t < N_T; ++t) {
        // ---- consume peers' packets (h_{t-1}, m_{t-1}) — u NOT polled here ----
        if (t > 0) {
            const u32 ep  = (u32)t;
            const int par = (t - 1) & 1;
            if (tid < 192) {
                const int pi = tid >> 6;
                const int q2 = pi + (pi >= q ? 1 : 0);
                const u32* base = pkt + (size_t)(par * 256 + b * 4 + q2) * PKT_STRIDE;
                const int i = tid & 63;
                u32 d0, d1, d2, d3;
                for (;;) {
                    d0 = aload(base + 4 * i + 0);
                    d1 = aload(base + 4 * i + 1);
                    d2 = aload(base + 4 * i + 2);
                    d3 = aload(base + 4 * i + 3);
                    if (((((d0 >> 16) ^ ep) | ((d1 >> 16) ^ ep)) |
                         (((d2 >> 16) ^ ep) | ((d3 >> 16) ^ ep))) == 0) break;
                }
                if (i < 32) {          // m: j = 2i, 2i+1 (hi,lo dword pairs)
                    int idx = 64 * q2 + 2 * i;
                    mf[idx]         = hbits2f(d0) + hbits2f(d1);
                    m_hi16[idx]     = (u16)d0;  m_lo16[idx]     = (u16)d1;
                    mf[idx + 1]     = hbits2f(d2) + hbits2f(d3);
                    m_hi16[idx + 1] = (u16)d2;  m_lo16[idx + 1] = (u16)d3;
                } else {               // h: c = 4i-128 .. +3
                    int idx = 128 * q2 + (4 * i - 128);
                    h_h16[idx]     = (u16)d0;
                    h_h16[idx + 1] = (u16)d1;
                    h_h16[idx + 2] = (u16)d2;
                    h_h16[idx + 3] = (u16)d3;
                }
            }
        }
        __syncthreads();                                   // B1

        // ---- z partials (old h, old m) + AT partials (old m) — all local ----
        {
            float z = 0.f;
            #pragma unroll
            for (int i = 0; i < 64; ++i)
                z = dot2f(h2u[64 * kg + i], hk_w[i], z);
            #pragma unroll
            for (int i = 0; i < 32; ++i) {
                u32 w = amk_w[i];
                z = dot2f(m_hi2[32 * kg + i], w, z);
                z = dot2f(m_lo2[32 * kg + i], w, z);
            }
            zbuf[tid] = z;
            float am = 0.f;
            #pragma unroll
            for (int i = 0; i < 32; ++i)
                am = fmaf(mf[32 * kg8 + i], at_w[i], am);
            ampart[tid] = am;
        }
        __syncthreads();                                   // B2

        // ---- u: direct spin-read of all 4 WGs' u-pairs (hidden behind z) ----
        float u = 0.f, mnew = 0.f, hnew = 0.f;
        u16 mhi_b = 0, mlo_b = 0;
        if (tid < 128) {
            u = xs[t] * ie0;
            if (t > 0) {
                const u32 ep  = (u32)t;
                const int par = (t - 1) & 1;
                u32 d[16];
                for (;;) {
                    #pragma unroll
                    for (int pq = 0; pq < 4; ++pq) {
                        const u32* pp = pkt + (size_t)(par * 256 + b * 4 + pq) * PKT_STRIDE + 256;
                        d[4 * pq + 0] = aload(pp + 0);
                        d[4 * pq + 1] = aload(pp + 1);
                        d[4 * pq + 2] = aload(pp + 2);
                        d[4 * pq + 3] = aload(pp + 3);
                    }
                    u32 bad = 0;
                    #pragma unroll
                    for (int i2 = 0; i2 < 16; ++i2) bad |= (d[i2] >> 16) ^ ep;
                    if (bad == 0) break;
                }
                float s = 0.f;
                #pragma unroll
                for (int i2 = 0; i2 < 16; ++i2) s += hbits2f(d[i2]);
                u += s;
            }
        }
        if (tid < 64) {
            mnew = mf[J] + u * bt_sl[tid];
            #pragma unroll
            for (int gi = 0; gi < 8; ++gi) mnew += ampart[tid + 64 * gi];
            _Float16 hi = (_Float16)mnew;
            float lo = mnew - (float)hi;
            mhi_b = __builtin_bit_cast(u16, hi);
            mlo_b = f2h_bits(lo);
            mf[J] = mnew;            // own slice stays exact fp32
            m_hi16[J] = mhi_b;
            m_lo16[J] = mlo_b;
        }
        if (tid < 128) {
            float zf = zbuf[tid] + zbuf[tid + 128] + zbuf[tid + 256] + zbuf[tid + 384]
                     + xs[t] * ik_sl[tid] + u * bmk_sl[tid];
            hnew = tanhf(zf);
            outb[(size_t)t * N_UNITS + 128 * q + tid] = hnew;
            h_h16[128 * q + tid] = f2h_bits(hnew);
        }

        if (t < N_T - 1) {
            // ---- publish own slices (self-validating dwords, no drain/flag) ----
            const u32 eph = (u32)(t + 1) << 16;
            u32* myb = pkt + (size_t)((t & 1) * 256 + b * 4 + q) * PKT_STRIDE;
            if (tid < 64) {
                astore(myb + 2 * tid,     (u32)mhi_b | eph);
                astore(myb + 2 * tid + 1, (u32)mlo_b | eph);
            }
            if (tid < 128)
                astore(myb + 128 + tid, (u32)f2h_bits(hnew) | eph);

            // ---- own u-partials for step t+1: per-wave reduce + direct publish ----
            float up = 0.f;
            if (tid < 128) {
                up = hnew * he_sl[tid];
                if (tid < 64) up = fmaf(mnew, me_sl[tid], up);
            }
            #pragma unroll
            for (int off = 32; off > 0; off >>= 1) up += __shfl_down(up, off);
            if (lane == 0 && tid < 128) {
                _Float16 hi = (_Float16)up;
                float lo = up - (float)hi;
                astore(myb + 256 + 2 * (tid >> 6),     (u32)__builtin_bit_cast(u16, hi) | eph);
                astore(myb + 256 + 2 * (tid >> 6) + 1, (u32)f2h_bits(lo) | eph);
            }
        }
        // (no B3 — B1 of the next iteration fences the zbuf/ampart WAR hazard)
    }
}

extern "C" void kernel_launch(void* const* d_in, const int* in_sizes, int n_in,
                              void* d_out, int out_size, void* d_ws, size_t ws_size,
                              hipStream_t stream) {
    const float* x  = (const float*)d_in[0];
    const float* ie = (const float*)d_in[1];
    const float* he = (const float*)d_in[2];
    const float* me = (const float*)d_in[3];
    const float* ik = (const float*)d_in[4];
    const float* hk = (const float*)d_in[5];
    const float* mk = (const float*)d_in[6];
    const float* at = (const float*)d_in[7];
    const float* bt = (const float*)d_in[8];

    u32*   hk2  = (u32*)d_ws;                   // 131072 u32 = 512 KB
    u32*   amk2 = hk2 + 256 * 512;              //  65536 u32 = 256 KB
    float* bmk  = (float*)(amk2 + 128 * 512);   //    512 f32 =   2 KB
    u32*   pkt  = (u32*)(bmk + 512);            // 2*64*4*288 u32 = 576 KB

    prep_hk<<<512, 256, 0, stream>>>(hk, hk2);
    prep_amk<<<129, 512, 0, stream>>>(mk, at, bt, amk2, bmk);
    lmu_main<<<N_B * KWG, 512, 0, stream>>>(x, ie, he, me, ik, bt, at,
                                            hk2, amk2, bmk, pkt, (float*)d_out);
}

// Round 5
// 2916.835 us; speedup vs baseline: 1.9489x; 1.1172x over previous
//
#include <hip/hip_runtime.h>
#include <hip/hip_fp16.h>

typedef unsigned int u32;
typedef unsigned short u16;
typedef _Float16 half2v __attribute__((ext_vector_type(2)));

#define N_UNITS 512
#define N_ORDER 256
#define N_T     1024
#define N_B     64
#define KWG     4
#define PKT_STRIDE 288   // dwords per (parity,b,q) packet: 128 m + 128 h + 2 u + pad

__device__ inline float dot2f(u32 a, u32 b, float acc) {
    return __builtin_amdgcn_fdot2(__builtin_bit_cast(half2v, a),
                                  __builtin_bit_cast(half2v, b), acc, false);
}
__device__ inline u16 f2h_bits(float v) {
    _Float16 f = (_Float16)v;
    return __builtin_bit_cast(u16, f);
}
__device__ inline float hbits2f(u32 dw) {
    u16 s = (u16)(dw & 0xFFFFu);
    _Float16 f = __builtin_bit_cast(_Float16, s);
    return (float)f;
}
__device__ inline u32 pack_h2(float a, float b) {
    return (u32)f2h_bits(a) | ((u32)f2h_bits(b) << 16);
}
__device__ inline u32 aload(const u32* p) {
    return __hip_atomic_load(p, __ATOMIC_RELAXED, __HIP_MEMORY_SCOPE_AGENT);
}
__device__ inline void astore(u32* p, u32 v) {
    __hip_atomic_store(p, v, __ATOMIC_RELAXED, __HIP_MEMORY_SCOPE_AGENT);
}

// hk2[kk][c] = half2(hk[2kk][c], hk[2kk+1][c]),  kk<256, c<512
__global__ __launch_bounds__(256)
void prep_hk(const float* __restrict__ hk, u32* __restrict__ hk2) {
    int tid = blockIdx.x * 256 + threadIdx.x;   // 131072 total
    int kk = tid >> 9, c = tid & 511;
    hk2[tid] = pack_h2(hk[(2 * kk) * 512 + c], hk[(2 * kk + 1) * 512 + c]);
}

// AMK = mk + AT@mk  (fp16, j-pair packed);  BMK = BT@mk (fp32)
// blocks 0..127: amk2[bj][c] = half2(AMK[2bj][c], AMK[2bj+1][c]); block 128: BMK
__global__ __launch_bounds__(512)
void prep_amk(const float* __restrict__ mk, const float* __restrict__ at,
              const float* __restrict__ bt,
              u32* __restrict__ amk2, float* __restrict__ bmk) {
    int bj = blockIdx.x, c = threadIdx.x;
    if (bj < 128) {
        int j0 = 2 * bj, j1 = j0 + 1;
        float a0 = mk[j0 * 512 + c];
        float a1 = mk[j1 * 512 + c];
        #pragma unroll 8
        for (int k = 0; k < 256; ++k) {
            float w = mk[k * 512 + c];
            a0 = fmaf(at[j0 * 256 + k], w, a0);
            a1 = fmaf(at[j1 * 256 + k], w, a1);
        }
        amk2[bj * 512 + c] = pack_h2(a0, a1);
    } else {
        float s = 0.f;
        #pragma unroll 8
        for (int k = 0; k < 256; ++k) s = fmaf(bt[k], mk[k * 512 + c], s);
        bmk[c] = s;
    }
}

// K=4 WGs per batch; grid=256 (1 WG/CU). g: b=g&63, q=g>>6 (same XCD mod-8).
// WG q owns h cols [128q,128q+128), m cols [64q,64q+64).
// Weights in VGPRs: hk 64 u32 + AMK 32 u32 + AT 32 f32.
// One cross-WG sync/step via self-validating packets (epoch in each dword's
// high16, dword stores are atomic) — no flags, no release, no producer drain.
// z refactor: m_new@mk = m_old@AMK + u*BMK with AMK = mk + AT@mk.
// Round-5 delta vs proven R0 (2887us): ONE change — the out store is
// nontemporal (nt), so the 128MB output stream bypasses L2 and stops
// evicting the packet lines the cross-WG spin gates on.
__global__ __launch_bounds__(512, 2)
void lmu_main(const float* __restrict__ x, const float* __restrict__ ie,
              const float* __restrict__ he, const float* __restrict__ me,
              const float* __restrict__ ik, const float* __restrict__ bt,
              const float* __restrict__ at,
              const u32* __restrict__ hk2, const u32* __restrict__ amk2,
              const float* __restrict__ bmk,
              u32* __restrict__ pkt, float* __restrict__ out) {
    __shared__ float xs[N_T];
    __shared__ float he_sl[128], ik_sl[128], bmk_sl[128];
    __shared__ float me_sl[64], bt_sl[64];
    __shared__ __align__(8) u16 h_h16[N_UNITS];     // full h, fp16
    __shared__ __align__(8) u16 m_hi16[N_ORDER], m_lo16[N_ORDER];
    __shared__ __align__(8) float mf[N_ORDER];      // full m, fp32(-ish)
    __shared__ float zbuf[512], ampart[512];
    __shared__ float upart[4];                      // u partials per q
    __shared__ float upw[2];

    const int tid = threadIdx.x;
    const int g   = blockIdx.x;
    const int b   = g & 63;
    const int q   = g >> 6;
    const int kg  = tid >> 7;        // 0..3 (hk/AMK k-group)
    const int cl  = tid & 127;       // col within own h slice
    const int kg8 = tid >> 6;        // 0..7 (AT k-group)
    const int jl  = tid & 63;
    const int J   = 64 * q + jl;
    const int lane = tid & 63;

    // ---- preload LDS ----
    for (int i = tid; i < N_T; i += 512) xs[i] = x[b * N_T + i];
    if (tid < 128) {
        he_sl[tid]  = he[128 * q + tid];
        ik_sl[tid]  = ik[128 * q + tid];
        bmk_sl[tid] = bmk[128 * q + tid];
    }
    if (tid < 64) { me_sl[tid] = me[J]; bt_sl[tid] = bt[J]; }
    h_h16[tid] = 0;
    if (tid < 256) { m_hi16[tid] = 0; m_lo16[tid] = 0; mf[tid] = 0.f; }
    if (tid < 4) upart[tid] = 0.f;
    const float ie0 = ie[0];

    // ---- weights into registers (once) ----
    u32 hk_w[64];
    #pragma unroll
    for (int i = 0; i < 64; ++i)
        hk_w[i] = hk2[(size_t)(64 * kg + i) * 512 + 128 * q + cl];
    u32 amk_w[32];
    #pragma unroll
    for (int i = 0; i < 32; ++i)
        amk_w[i] = amk2[(size_t)(32 * kg + i) * 512 + 128 * q + cl];
    float at_w[32];
    #pragma unroll
    for (int i = 0; i < 32; ++i)
        at_w[i] = at[(size_t)(32 * kg8 + i) * 256 + J];

    __syncthreads();

    const u32* h2u   = reinterpret_cast<const u32*>(h_h16);
    const u32* m_hi2 = reinterpret_cast<const u32*>(m_hi16);
    const u32* m_lo2 = reinterpret_cast<const u32*>(m_lo16);
    float* outb = out + (size_t)b * N_T * N_UNITS;

    for (int t = 0; t < N_T; ++t) {
        // ---- consume peers' packets (h_{t-1}, m_{t-1}, u-partials) ----
        if (t > 0) {
            const u32 ep  = (u32)t;
            const int par = (t - 1) & 1;
            if (tid < 195) {
                int pi = (tid < 192) ? (tid >> 6) : (tid - 192);
                int q2 = pi + (pi >= q ? 1 : 0);
                const u32* base = pkt + (size_t)(par * 256 + b * 4 + q2) * PKT_STRIDE;
                if (tid < 192) {
                    int i = tid & 63;
                    u32 d0, d1, d2, d3;
                    for (;;) {
                        d0 = aload(base + 4 * i + 0);
                        d1 = aload(base + 4 * i + 1);
                        d2 = aload(base + 4 * i + 2);
                        d3 = aload(base + 4 * i + 3);
                        if (((((d0 >> 16) ^ ep) | ((d1 >> 16) ^ ep)) |
                             (((d2 >> 16) ^ ep) | ((d3 >> 16) ^ ep))) == 0) break;
                    }
                    if (i < 32) {          // m: j = 2i, 2i+1 (hi,lo dword pairs)
                        int idx = 64 * q2 + 2 * i;
                        mf[idx]         = hbits2f(d0) + hbits2f(d1);
                        m_hi16[idx]     = (u16)d0;  m_lo16[idx]     = (u16)d1;
                        mf[idx + 1]     = hbits2f(d2) + hbits2f(d3);
                        m_hi16[idx + 1] = (u16)d2;  m_lo16[idx + 1] = (u16)d3;
                    } else {               // h: c = 4i-128 .. +3
                        int idx = 128 * q2 + (4 * i - 128);
                        h_h16[idx]     = (u16)d0;
                        h_h16[idx + 1] = (u16)d1;
                        h_h16[idx + 2] = (u16)d2;
                        h_h16[idx + 3] = (u16)d3;
                    }
                } else {                   // u partial (hi/lo dwords)
                    u32 d0, d1;
                    for (;;) {
                        d0 = aload(base + 256);
                        d1 = aload(base + 257);
                        if ((((d0 >> 16) ^ ep) | ((d1 >> 16) ^ ep)) == 0) break;
                    }
                    upart[q2] = hbits2f(d0) + hbits2f(d1);
                }
            }
        }
        __syncthreads();                                   // B1

        // ---- z partials (old h, old m) + AT partials (old m) — all local ----
        {
            float z = 0.f;
            #pragma unroll
            for (int i = 0; i < 64; ++i)
                z = dot2f(h2u[64 * kg + i], hk_w[i], z);
            #pragma unroll
            for (int i = 0; i < 32; ++i) {
                u32 w = amk_w[i];
                z = dot2f(m_hi2[32 * kg + i], w, z);
                z = dot2f(m_lo2[32 * kg + i], w, z);
            }
            zbuf[tid] = z;
            float am = 0.f;
            #pragma unroll
            for (int i = 0; i < 32; ++i)
                am = fmaf(mf[32 * kg8 + i], at_w[i], am);
            ampart[tid] = am;
        }
        __syncthreads();                                   // B2

        // ---- finalize: u, m_new slice, h_new slice ----
        float u = 0.f, mnew = 0.f, hnew = 0.f;
        u16 mhi_b = 0, mlo_b = 0;
        if (tid < 128)
            u = upart[0] + upart[1] + upart[2] + upart[3] + xs[t] * ie0;
        if (tid < 64) {
            mnew = mf[J] + u * bt_sl[tid];
            #pragma unroll
            for (int gi = 0; gi < 8; ++gi) mnew += ampart[tid + 64 * gi];
            _Float16 hi = (_Float16)mnew;
            float lo = mnew - (float)hi;
            mhi_b = __builtin_bit_cast(u16, hi);
            mlo_b = f2h_bits(lo);
            mf[J] = mnew;            // own slice stays exact fp32
            m_hi16[J] = mhi_b;
            m_lo16[J] = mlo_b;
        }
        if (tid < 128) {
            float zf = zbuf[tid] + zbuf[tid + 128] + zbuf[tid + 256] + zbuf[tid + 384]
                     + xs[t] * ik_sl[tid] + u * bmk_sl[tid];
            hnew = tanhf(zf);
            __builtin_nontemporal_store(hnew, &outb[(size_t)t * N_UNITS + 128 * q + tid]);
            h_h16[128 * q + tid] = f2h_bits(hnew);
        }

        if (t < N_T - 1) {
            // ---- publish own slices (self-validating dwords, no drain/flag) ----
            const u32 eph = (u32)(t + 1) << 16;
            u32* myb = pkt + (size_t)((t & 1) * 256 + b * 4 + q) * PKT_STRIDE;
            if (tid < 64) {
                astore(myb + 2 * tid,     (u32)mhi_b | eph);
                astore(myb + 2 * tid + 1, (u32)mlo_b | eph);
            }
            if (tid < 128)
                astore(myb + 128 + tid, (u32)f2h_bits(hnew) | eph);

            // ---- own u-partial for step t+1 ----
            float up = 0.f;
            if (tid < 128) {
                up = hnew * he_sl[tid];
                if (tid < 64) up = fmaf(mnew, me_sl[tid], up);
            }
            #pragma unroll
            for (int off = 32; off > 0; off >>= 1) up += __shfl_down(up, off);
            if (lane == 0 && tid < 128) upw[tid >> 6] = up;
            __syncthreads();                               // B3
            if (tid == 0) {
                float myu = upw[0] + upw[1];
                upart[q] = myu;
                _Float16 hi = (_Float16)myu;
                float lo = myu - (float)hi;
                astore(myb + 256, (u32)__builtin_bit_cast(u16, hi) | eph);
                astore(myb + 257, (u32)f2h_bits(lo) | eph);
            }
        }
    }
}

extern "C" void kernel_launch(void* const* d_in, const int* in_sizes, int n_in,
                              void* d_out, int out_size, void* d_ws, size_t ws_size,
                              hipStream_t stream) {
    const float* x  = (const float*)d_in[0];
    const float* ie = (const float*)d_in[1];
    const float* he = (const float*)d_in[2];
    const float* me = (const float*)d_in[3];
    const float* ik = (const float*)d_in[4];
    const float* hk = (const float*)d_in[5];
    const float* mk = (const float*)d_in[6];
    const float* at = (const float*)d_in[7];
    const float* bt = (const float*)d_in[8];

    u32*   hk2  = (u32*)d_ws;                   // 131072 u32 = 512 KB
    u32*   amk2 = hk2 + 256 * 512;              //  65536 u32 = 256 KB
    float* bmk  = (float*)(amk2 + 128 * 512);   //    512 f32 =   2 KB
    u32*   pkt  = (u32*)(bmk + 512);            // 2*64*4*288 u32 = 576 KB

    prep_hk<<<512, 256, 0, stream>>>(hk, hk2);
    prep_amk<<<129, 512, 0, stream>>>(mk, at, bt, amk2, bmk);
    lmu_main<<<N_B * KWG, 512, 0, stream>>>(x, ie, he, me, ik, bt, at,
                                            hk2, amk2, bmk, pkt, (float*)d_out);
}

// Round 6
// 2760.020 us; speedup vs baseline: 2.0596x; 1.0568x over previous
//
#include <hip/hip_runtime.h>
#include <hip/hip_fp16.h>

typedef unsigned int u32;
typedef unsigned short u16;
typedef _Float16 half2v __attribute__((ext_vector_type(2)));
typedef u32 u32x4 __attribute__((ext_vector_type(4)));
typedef u32 u32x2 __attribute__((ext_vector_type(2)));

#define N_UNITS 512
#define N_ORDER 256
#define N_T     1024
#define N_B     64
#define KWG     4
#define PKT_STRIDE 288   // dwords per (parity,b,q) packet: 128 m + 128 h + 2 u + pad

__device__ inline float dot2f(u32 a, u32 b, float acc) {
    return __builtin_amdgcn_fdot2(__builtin_bit_cast(half2v, a),
                                  __builtin_bit_cast(half2v, b), acc, false);
}
__device__ inline u16 f2h_bits(float v) {
    _Float16 f = (_Float16)v;
    return __builtin_bit_cast(u16, f);
}
__device__ inline float hbits2f(u32 dw) {
    u16 s = (u16)(dw & 0xFFFFu);
    _Float16 f = __builtin_bit_cast(_Float16, s);
    return (float)f;
}
__device__ inline u32 pack_h2(float a, float b) {
    return (u32)f2h_bits(a) | ((u32)f2h_bits(b) << 16);
}
__device__ inline u32 aload(const u32* p) {
    return __hip_atomic_load(p, __ATOMIC_RELAXED, __HIP_MEMORY_SCOPE_AGENT);
}
__device__ inline void astore(u32* p, u32 v) {
    __hip_atomic_store(p, v, __ATOMIC_RELAXED, __HIP_MEMORY_SCOPE_AGENT);
}
// Wide coherent packet ops: ONE request to the coherence point instead of 2/4.
// sc0 sc1 = system-scope cache bypass on gfx950 (per-dword atomicity of an
// aligned dwordx4/x2 is architectural; each dword self-validates via epoch).
__device__ inline u32x4 aload4(const u32* p) {
    u32x4 r;
    asm volatile("global_load_dwordx4 %0, %1, off sc0 sc1\n\ts_waitcnt vmcnt(0)"
                 : "=&v"(r) : "v"(p) : "memory");
    return r;
}
__device__ inline u32x2 aload2(const u32* p) {
    u32x2 r;
    asm volatile("global_load_dwordx2 %0, %1, off sc0 sc1\n\ts_waitcnt vmcnt(0)"
                 : "=&v"(r) : "v"(p) : "memory");
    return r;
}
__device__ inline void astore2(u32* p, u32 a, u32 b) {
    u32x2 v; v.x = a; v.y = b;
    asm volatile("global_store_dwordx2 %0, %1, off sc0 sc1"
                 :: "v"(p), "v"(v) : "memory");
}

// hk2[kk][c] = half2(hk[2kk][c], hk[2kk+1][c]),  kk<256, c<512
__global__ __launch_bounds__(256)
void prep_hk(const float* __restrict__ hk, u32* __restrict__ hk2) {
    int tid = blockIdx.x * 256 + threadIdx.x;   // 131072 total
    int kk = tid >> 9, c = tid & 511;
    hk2[tid] = pack_h2(hk[(2 * kk) * 512 + c], hk[(2 * kk + 1) * 512 + c]);
}

// AMK = mk + AT@mk  (fp16, j-pair packed);  BMK = BT@mk (fp32)
// blocks 0..127: amk2[bj][c] = half2(AMK[2bj][c], AMK[2bj+1][c]); block 128: BMK
__global__ __launch_bounds__(512)
void prep_amk(const float* __restrict__ mk, const float* __restrict__ at,
              const float* __restrict__ bt,
              u32* __restrict__ amk2, float* __restrict__ bmk) {
    int bj = blockIdx.x, c = threadIdx.x;
    if (bj < 128) {
        int j0 = 2 * bj, j1 = j0 + 1;
        float a0 = mk[j0 * 512 + c];
        float a1 = mk[j1 * 512 + c];
        #pragma unroll 8
        for (int k = 0; k < 256; ++k) {
            float w = mk[k * 512 + c];
            a0 = fmaf(at[j0 * 256 + k], w, a0);
            a1 = fmaf(at[j1 * 256 + k], w, a1);
        }
        amk2[bj * 512 + c] = pack_h2(a0, a1);
    } else {
        float s = 0.f;
        #pragma unroll 8
        for (int k = 0; k < 256; ++k) s = fmaf(bt[k], mk[k * 512 + c], s);
        bmk[c] = s;
    }
}

// K=4 WGs per batch; grid=256 (1 WG/CU). g: b=g&63, q=g>>6 (same XCD mod-8).
// WG q owns h cols [128q,128q+128), m cols [64q,64q+64).
// Weights in VGPRs: hk 64 u32 + AMK 32 u32 + AT 32 f32.
// One cross-WG sync/step via self-validating packets (epoch in each dword's
// high16, dword stores are atomic) — no flags, no release, no producer drain.
// Round-6 delta vs R5 (2916us ≈ R0 2887us): packet path uses WIDE coherent
// ops (dwordx4 spin loads, dwordx2 m/u publishes) — 4x fewer requests at the
// cross-XCD coherence point per spin iteration. Choreography unchanged.
__global__ __launch_bounds__(512, 2)
void lmu_main(const float* __restrict__ x, const float* __restrict__ ie,
              const float* __restrict__ he, const float* __restrict__ me,
              const float* __restrict__ ik, const float* __restrict__ bt,
              const float* __restrict__ at,
              const u32* __restrict__ hk2, const u32* __restrict__ amk2,
              const float* __restrict__ bmk,
              u32* __restrict__ pkt, float* __restrict__ out) {
    __shared__ float xs[N_T];
    __shared__ float he_sl[128], ik_sl[128], bmk_sl[128];
    __shared__ float me_sl[64], bt_sl[64];
    __shared__ __align__(8) u16 h_h16[N_UNITS];     // full h, fp16
    __shared__ __align__(8) u16 m_hi16[N_ORDER], m_lo16[N_ORDER];
    __shared__ __align__(8) float mf[N_ORDER];      // full m, fp32(-ish)
    __shared__ float zbuf[512], ampart[512];
    __shared__ float upart[4];                      // u partials per q
    __shared__ float upw[2];

    const int tid = threadIdx.x;
    const int g   = blockIdx.x;
    const int b   = g & 63;
    const int q   = g >> 6;
    const int kg  = tid >> 7;        // 0..3 (hk/AMK k-group)
    const int cl  = tid & 127;       // col within own h slice
    const int kg8 = tid >> 6;        // 0..7 (AT k-group)
    const int jl  = tid & 63;
    const int J   = 64 * q + jl;
    const int lane = tid & 63;

    // ---- preload LDS ----
    for (int i = tid; i < N_T; i += 512) xs[i] = x[b * N_T + i];
    if (tid < 128) {
        he_sl[tid]  = he[128 * q + tid];
        ik_sl[tid]  = ik[128 * q + tid];
        bmk_sl[tid] = bmk[128 * q + tid];
    }
    if (tid < 64) { me_sl[tid] = me[J]; bt_sl[tid] = bt[J]; }
    h_h16[tid] = 0;
    if (tid < 256) { m_hi16[tid] = 0; m_lo16[tid] = 0; mf[tid] = 0.f; }
    if (tid < 4) upart[tid] = 0.f;
    const float ie0 = ie[0];

    // ---- weights into registers (once) ----
    u32 hk_w[64];
    #pragma unroll
    for (int i = 0; i < 64; ++i)
        hk_w[i] = hk2[(size_t)(64 * kg + i) * 512 + 128 * q + cl];
    u32 amk_w[32];
    #pragma unroll
    for (int i = 0; i < 32; ++i)
        amk_w[i] = amk2[(size_t)(32 * kg + i) * 512 + 128 * q + cl];
    float at_w[32];
    #pragma unroll
    for (int i = 0; i < 32; ++i)
        at_w[i] = at[(size_t)(32 * kg8 + i) * 256 + J];

    __syncthreads();

    const u32* h2u   = reinterpret_cast<const u32*>(h_h16);
    const u32* m_hi2 = reinterpret_cast<const u32*>(m_hi16);
    const u32* m_lo2 = reinterpret_cast<const u32*>(m_lo16);
    float* outb = out + (size_t)b * N_T * N_UNITS;

    for (int t = 0; t < N_T; ++t) {
        // ---- consume peers' packets (h_{t-1}, m_{t-1}, u-partials) ----
        if (t > 0) {
            const u32 ep  = (u32)t;
            const int par = (t - 1) & 1;
            if (tid < 195) {
                int pi = (tid < 192) ? (tid >> 6) : (tid - 192);
                int q2 = pi + (pi >= q ? 1 : 0);
                const u32* base = pkt + (size_t)(par * 256 + b * 4 + q2) * PKT_STRIDE;
                if (tid < 192) {
                    int i = tid & 63;
                    u32 d0, d1, d2, d3;
                    for (;;) {
                        u32x4 dv = aload4(base + 4 * i);
                        d0 = dv.x; d1 = dv.y; d2 = dv.z; d3 = dv.w;
                        if (((((d0 >> 16) ^ ep) | ((d1 >> 16) ^ ep)) |
                             (((d2 >> 16) ^ ep) | ((d3 >> 16) ^ ep))) == 0) break;
                    }
                    if (i < 32) {          // m: j = 2i, 2i+1 (hi,lo dword pairs)
                        int idx = 64 * q2 + 2 * i;
                        mf[idx]         = hbits2f(d0) + hbits2f(d1);
                        m_hi16[idx]     = (u16)d0;  m_lo16[idx]     = (u16)d1;
                        mf[idx + 1]     = hbits2f(d2) + hbits2f(d3);
                        m_hi16[idx + 1] = (u16)d2;  m_lo16[idx + 1] = (u16)d3;
                    } else {               // h: c = 4i-128 .. +3
                        int idx = 128 * q2 + (4 * i - 128);
                        h_h16[idx]     = (u16)d0;
                        h_h16[idx + 1] = (u16)d1;
                        h_h16[idx + 2] = (u16)d2;
                        h_h16[idx + 3] = (u16)d3;
                    }
                } else {                   // u partial (hi/lo dwords, one dwordx2)
                    u32 d0, d1;
                    for (;;) {
                        u32x2 dv = aload2(base + 256);
                        d0 = dv.x; d1 = dv.y;
                        if ((((d0 >> 16) ^ ep) | ((d1 >> 16) ^ ep)) == 0) break;
                    }
                    upart[q2] = hbits2f(d0) + hbits2f(d1);
                }
            }
        }
        __syncthreads();                                   // B1

        // ---- z partials (old h, old m) + AT partials (old m) — all local ----
        {
            float z = 0.f;
            #pragma unroll
            for (int i = 0; i < 64; ++i)
                z = dot2f(h2u[64 * kg + i], hk_w[i], z);
            #pragma unroll
            for (int i = 0; i < 32; ++i) {
                u32 w = amk_w[i];
                z = dot2f(m_hi2[32 * kg + i], w, z);
                z = dot2f(m_lo2[32 * kg + i], w, z);
            }
            zbuf[tid] = z;
            float am = 0.f;
            #pragma unroll
            for (int i = 0; i < 32; ++i)
                am = fmaf(mf[32 * kg8 + i], at_w[i], am);
            ampart[tid] = am;
        }
        __syncthreads();                                   // B2

        // ---- finalize: u, m_new slice, h_new slice ----
        float u = 0.f, mnew = 0.f, hnew = 0.f;
        u16 mhi_b = 0, mlo_b = 0;
        if (tid < 128)
            u = upart[0] + upart[1] + upart[2] + upart[3] + xs[t] * ie0;
        if (tid < 64) {
            mnew = mf[J] + u * bt_sl[tid];
            #pragma unroll
            for (int gi = 0; gi < 8; ++gi) mnew += ampart[tid + 64 * gi];
            _Float16 hi = (_Float16)mnew;
            float lo = mnew - (float)hi;
            mhi_b = __builtin_bit_cast(u16, hi);
            mlo_b = f2h_bits(lo);
            mf[J] = mnew;            // own slice stays exact fp32
            m_hi16[J] = mhi_b;
            m_lo16[J] = mlo_b;
        }
        if (tid < 128) {
            float zf = zbuf[tid] + zbuf[tid + 128] + zbuf[tid + 256] + zbuf[tid + 384]
                     + xs[t] * ik_sl[tid] + u * bmk_sl[tid];
            hnew = tanhf(zf);
            __builtin_nontemporal_store(hnew, &outb[(size_t)t * N_UNITS + 128 * q + tid]);
            h_h16[128 * q + tid] = f2h_bits(hnew);
        }

        if (t < N_T - 1) {
            // ---- publish own slices (self-validating dwords, no drain/flag) ----
            const u32 eph = (u32)(t + 1) << 16;
            u32* myb = pkt + (size_t)((t & 1) * 256 + b * 4 + q) * PKT_STRIDE;
            if (tid < 64)
                astore2(myb + 2 * tid, (u32)mhi_b | eph, (u32)mlo_b | eph);
            if (tid < 128)
                astore(myb + 128 + tid, (u32)f2h_bits(hnew) | eph);

            // ---- own u-partial for step t+1 ----
            float up = 0.f;
            if (tid < 128) {
                up = hnew * he_sl[tid];
                if (tid < 64) up = fmaf(mnew, me_sl[tid], up);
            }
            #pragma unroll
            for (int off = 32; off > 0; off >>= 1) up += __shfl_down(up, off);
            if (lane == 0 && tid < 128) upw[tid >> 6] = up;
            __syncthreads();                               // B3
            if (tid == 0) {
                float myu = upw[0] + upw[1];
                upart[q] = myu;
                _Float16 hi = (_Float16)myu;
                float lo = myu - (float)hi;
                astore2(myb + 256, (u32)__builtin_bit_cast(u16, hi) | eph,
                                   (u32)f2h_bits(lo) | eph);
            }
        }
    }
}

extern "C" void kernel_launch(void* const* d_in, const int* in_sizes, int n_in,
                              void* d_out, int out_size, void* d_ws, size_t ws_size,
                              hipStream_t stream) {
    const float* x  = (const float*)d_in[0];
    const float* ie = (const float*)d_in[1];
    const float* he = (const float*)d_in[2];
    const float* me = (const float*)d_in[3];
    const float* ik = (const float*)d_in[4];
    const float* hk = (const float*)d_in[5];
    const float* mk = (const float*)d_in[6];
    const float* at = (const float*)d_in[7];
    const float* bt = (const float*)d_in[8];

    u32*   hk2  = (u32*)d_ws;                   // 131072 u32 = 512 KB
    u32*   amk2 = hk2 + 256 * 512;              //  65536 u32 = 256 KB
    float* bmk  = (float*)(amk2 + 128 * 512);   //    512 f32 =   2 KB
    u32*   pkt  = (u32*)(bmk + 512);            // 2*64*4*288 u32 = 576 KB

    prep_hk<<<512, 256, 0, stream>>>(hk, hk2);
    prep_amk<<<129, 512, 0, stream>>>(mk, at, bt, amk2, bmk);
    lmu_main<<<N_B * KWG, 512, 0, stream>>>(x, ie, he, me, ik, bt, at,
                                            hk2, amk2, bmk, pkt, (float*)d_out);
}